// Round 9
// baseline (184.689 us; speedup 1.0000x reference)
//
#include <hip/hip_runtime.h>
#include <stdint.h>

// ---------------------------------------------------------------------------
// MultiHeadAttention B=4 T=2048 C=1024 H=16 D=64  (fp32 in/out, causal)
// Pipeline: cvt(bf16, fused) -> GEMM(QKV, v transposed) -> flash-attn -> GEMM(proj)+bias
// Round-9: byte-exact round-6 attn (known-pass) + fused cvt + GEMM XCD swizzle.
// ---------------------------------------------------------------------------

typedef unsigned short u16;
typedef __attribute__((ext_vector_type(8))) short    s16x8;
typedef __attribute__((ext_vector_type(4))) float    f32x4;
typedef __attribute__((ext_vector_type(2))) uint32_t u32x2;

// --- helpers ---------------------------------------------------------------

__device__ __forceinline__ u16 f2b(float f) {  // f32 -> bf16 RNE
  union { float f; uint32_t u; } v; v.f = f;
  uint32_t r = v.u + 0x7FFFu + ((v.u >> 16) & 1u);
  return (u16)(r >> 16);
}

__device__ __forceinline__ uint32_t cvtpk(float a, float b) {  // [lo=bf16(a), hi=bf16(b)]
  uint32_t r;
  asm("v_cvt_pk_bf16_f32 %0, %1, %2" : "=v"(r) : "v"(a), "v"(b));
  return r;
}

// v_mfma_f32_16x16x32_bf16. A: lane holds A[m=l&15][8k contig]; B: B^T[n=l&15][8k contig]
// C/D: row=(l>>4)*4+reg, col=l&15
__device__ __forceinline__ f32x4 mfma_bf16(s16x8 a, s16x8 b, f32x4 c) {
  asm("v_mfma_f32_16x16x32_bf16 %0, %1, %2, %0" : "+v"(c) : "v"(a), "v"(b));
  return c;
}

// async global->LDS, 16B per lane. LDS dest is wave-uniform base + lane*16.
__device__ __forceinline__ void gload_lds16(const void* g, void* l) {
  __builtin_amdgcn_global_load_lds(
      (__attribute__((address_space(1))) void*)(uintptr_t)g,
      (__attribute__((address_space(3))) void*)(uint32_t)(uintptr_t)l,
      16, 0, 0);
}

// --- fused conversion kernel -------------------------------------------------
// blocks [0,4096): x -> xb (8 elems/thread)
// blocks [4096,4608): Wp -> wpb (8 elems/thread)
// blocks [4608,16896): Wq/Wk/Wv gather -> wqkvb [3*H*D][C] (1 elem/thread)

__global__ void cvt_all_kernel(const float* __restrict__ x, const float* __restrict__ Wq,
                               const float* __restrict__ Wk, const float* __restrict__ Wv,
                               const float* __restrict__ Wp, u16* __restrict__ xb,
                               u16* __restrict__ wqkvb, u16* __restrict__ wpb) {
  int bid = blockIdx.x;
  if (bid < 4608) {
    const float* src = (bid < 4096) ? x : Wp;
    u16* dst = (bid < 4096) ? xb : wpb;
    size_t i = (size_t)((bid < 4096) ? bid : (bid - 4096)) * 256 + threadIdx.x;
    const f32x4* pp = (const f32x4*)(src + i * 8);
    f32x4 a = pp[0], b2 = pp[1];
    s16x8 o;
    o[0]=(short)f2b(a[0]); o[1]=(short)f2b(a[1]); o[2]=(short)f2b(a[2]); o[3]=(short)f2b(a[3]);
    o[4]=(short)f2b(b2[0]); o[5]=(short)f2b(b2[1]); o[6]=(short)f2b(b2[2]); o[7]=(short)f2b(b2[3]);
    *(s16x8*)(dst + i * 8) = o;
  } else {
    int idx = (bid - 4608) * 256 + threadIdx.x;
    int sel = idx >> 20;
    int rem = idx & 1048575;
    int n = rem >> 10, c = rem & 1023;
    int h = n >> 6, d = n & 63;
    const float* W = (sel == 0) ? Wq : ((sel == 1) ? Wk : Wv);
    wqkvb[idx] = f2b(W[h * 65536 + c * 64 + d]);
  }
}

// --- GEMM: C[M][N] = A[M][K] * B[N][K]^T  (bf16 in, 128x128 tile, BK=64) ----
// MODE 1: f32 out + bias.  MODE 2: qkv: cols<2048 -> bf16 C; v cols -> vT transposed.
// XCD-chunked block swizzle (bijective; grid count % 8 == 0).

template <int MODE>
__global__ __launch_bounds__(256) void gemm_bt_kernel(
    const u16* __restrict__ A, const u16* __restrict__ B, void* __restrict__ Cout,
    const float* __restrict__ bias, u16* __restrict__ vTout, int K, int ldc)
{
  __shared__ __attribute__((aligned(16))) u16 As[128 * 64];
  __shared__ __attribute__((aligned(16))) u16 Bs[128 * 64];

  const int tid  = threadIdx.x;
  const int lane = tid & 63;
  const int w    = tid >> 6;
  const int wm   = w >> 1, wn = w & 1;
  const int g    = lane >> 4;
  const int li   = lane & 15;

  // XCD-chunked swizzle: consecutive blocks within an XCD share the B panel
  const int nbx = gridDim.x;
  const int nb  = nbx * gridDim.y;
  const int bid = blockIdx.x + nbx * blockIdx.y;
  const int chunk = nb >> 3;
  const int bid2 = (bid & 7) * chunk + (bid >> 3);
  const size_t bm = (size_t)(bid2 % nbx) * 128;
  const size_t bn = (size_t)(bid2 / nbx) * 128;

  f32x4 acc[4][4] = {};

  const int kIters = K >> 6;
  for (int kt = 0; kt < kIters; ++kt) {
    const int kb = kt * 64;
#pragma unroll
    for (int i = 0; i < 4; ++i) {
      int c = i * 256 + tid;
      int row = c >> 3, sl = c & 7;
      int ss = sl ^ (row & 7);
      gload_lds16(A + (bm + row) * K + kb + ss * 8, &As[c * 8]);
      gload_lds16(B + (bn + row) * K + kb + ss * 8, &Bs[c * 8]);
    }
    __syncthreads();
#pragma unroll
    for (int ks = 0; ks < 2; ++ks) {
      s16x8 af[4], bfr[4];
#pragma unroll
      for (int f = 0; f < 4; ++f) {
        int ra = wm * 64 + f * 16 + li;
        int sa = (ks * 4 + g) ^ (ra & 7);
        af[f] = *(const s16x8*)&As[ra * 64 + sa * 8];
        int rb = wn * 64 + f * 16 + li;
        int sb = (ks * 4 + g) ^ (rb & 7);
        bfr[f] = *(const s16x8*)&Bs[rb * 64 + sb * 8];
      }
#pragma unroll
      for (int mi = 0; mi < 4; ++mi)
#pragma unroll
        for (int ni = 0; ni < 4; ++ni)
          acc[mi][ni] = mfma_bf16(af[mi], bfr[ni], acc[mi][ni]);
    }
    __syncthreads();
  }

  if constexpr (MODE == 1) {
#pragma unroll
    for (int ni = 0; ni < 4; ++ni) {
      size_t col = bn + wn * 64 + ni * 16 + li;
      float bv = bias[col];
#pragma unroll
      for (int mi = 0; mi < 4; ++mi)
#pragma unroll
        for (int r = 0; r < 4; ++r) {
          size_t row = bm + wm * 64 + mi * 16 + g * 4 + r;
          ((float*)Cout)[row * ldc + col] = acc[mi][ni][r] + bv;
        }
    }
  } else {
    if (bn < 2048) {                 // q|k region: bf16 into qkv
#pragma unroll
      for (int ni = 0; ni < 4; ++ni) {
        size_t col = bn + wn * 64 + ni * 16 + li;
#pragma unroll
        for (int mi = 0; mi < 4; ++mi)
#pragma unroll
          for (int r = 0; r < 4; ++r) {
            size_t row = bm + wm * 64 + mi * 16 + g * 4 + r;
            ((u16*)Cout)[row * ldc + col] = f2b(acc[mi][ni][r]);
          }
      }
    } else {                         // v region: write transposed into vT[bh][d][t]
      const int hb = (int)((bn - 2048) >> 6) + wn;
      const int bb = (int)(bm >> 11);
      const int t0b = ((int)bm & 2047) + wm * 64 + g * 4;
      u16* vrow = vTout + (size_t)((bb * 16 + hb) * 64) * 2048;
#pragma unroll
      for (int ni = 0; ni < 4; ++ni) {
        u16* vd_ = vrow + (size_t)(ni * 16 + li) * 2048;
#pragma unroll
        for (int mi = 0; mi < 4; ++mi) {
          u32x2 wv = { cvtpk(acc[mi][ni][0], acc[mi][ni][1]),
                       cvtpk(acc[mi][ni][2], acc[mi][ni][3]) };
          *(u32x2*)&vd_[t0b + mi * 16] = wv;
        }
      }
    }
  }
}

// --- flash attention (causal) v6 — byte-exact round-6 version (known pass) ---
// QBLK=64 (4 waves x 16 q), 1024 blocks, 40KB LDS -> 4 blocks/CU.
// Per-lane lrow partials; __any-gated max-reduce; causal pairing p=0..15.
// Double-buffered K/V, prefetch-before-compute, one __syncthreads per iter.

__global__ __launch_bounds__(256, 4) void attn_kernel(const u16* __restrict__ qkv,
                                                      const u16* __restrict__ vT,
                                                      u16* __restrict__ out) {
  __shared__ __attribute__((aligned(16))) u16 Ks[2][64 * 64];
  __shared__ __attribute__((aligned(16))) u16 Vs[2][64 * 64];
  __shared__ __attribute__((aligned(16))) u16 Ps[4][16 * 64];

  const int id  = blockIdx.x;                // 1024 blocks
  const int xcd = id & 7;
  const int rr  = id >> 3;
  const int bh  = xcd * 8 + (rr & 7);        // 8 bh per XCD
  const int p   = rr >> 3;                   // 0..15

  const int b = bh >> 4, h = bh & 15;
  const int tid = threadIdx.x;
  const int lane = tid & 63;
  const int w = tid >> 6;
  const int g = lane >> 4, li = lane & 15;

  const int tA = 31 - p;
  const int nA = tA + 1;
  const int nTot = 33;                       // nA + p + 1

  const u16* kbase = qkv + (size_t)(b * 2048) * 3072 + 1024 + h * 64;
  const u16* vtb   = vT + (size_t)bh * 64 * 2048;
  u16* pl = Ps[w];

  // hoisted per-lane offsets
  const int srow = tid >> 3;
  const int ssl0 = (tid & 7) ^ (srow & 7);
  const int kge0 = srow * 3072 + ssl0 * 8;
  const int vge0 = srow * 2048 + ssl0 * 8;
  u16* const kd0 = &Ks[0][tid * 8];
  u16* const vd0 = &Vs[0][tid * 8];

  int foff[2][4];                            // kf/vf fragment offsets
#pragma unroll
  for (int kk = 0; kk < 2; ++kk)
#pragma unroll
    for (int fj = 0; fj < 4; ++fj) {
      int rk = fj * 16 + li;
      foff[kk][fj] = rk * 64 + (((kk * 4 + g) ^ (rk & 7)) * 8);
    }
  const int lsw = li & 14;
  int pwoff[4], proff[2];
#pragma unroll
  for (int fj = 0; fj < 4; ++fj) pwoff[fj] = li * 64 + (((4 * fj + g) ^ lsw) * 4);
#pragma unroll
  for (int kk = 0; kk < 2; ++kk) proff[kk] = li * 64 + (((8 * kk + 2 * g) ^ lsw) * 4);

  auto stage = [&](int buf, int j0) {
    const u16* kp = kbase + (size_t)j0 * 3072;
    const u16* vp = vtb + j0;
    u16* kd = kd0 + buf * 4096;
    u16* vd = vd0 + buf * 4096;
    gload_lds16(kp + kge0, kd);
    gload_lds16(kp + kge0 + 32 * 3072, kd + 2048);
    gload_lds16(vp + vge0, vd);
    gload_lds16(vp + vge0 + 32 * 2048, vd + 2048);
  };

  stage(0, 0);
  __syncthreads();

  s16x8 qf[2];
  f32x4 oacc[4];
  float mrow = -1e30f, lrowp = 0.f;
  int qglob = 0;
  const float cexp = 0.18033688011112042f;   // (1/sqrt(64)) * log2(e)
  const float thr = 8.0f;

  for (int s = 0; s < nTot; ++s) {
    const int cur = s & 1;
    const bool inA = s < nA;
    const int t  = inA ? s : s - nA;
    const int qt = inA ? tA : p;
    const int j0 = t * 64;

    if (s + 1 < nTot) {                      // prefetch next tile before compute
      int t1 = (s + 1 < nA) ? (s + 1) : (s + 1 - nA);
      stage(cur ^ 1, t1 * 64);
    }

    if (t == 0) {                            // new q-tile: load Q frags, reset state
      qglob = qt * 64 + w * 16 + li;
      const u16* qbase = qkv + (size_t)(b * 2048 + qglob) * 3072 + h * 64;
#pragma unroll
      for (int kk = 0; kk < 2; ++kk)
        qf[kk] = *(const s16x8*)&qbase[kk * 32 + g * 8];
      mrow = -1e30f; lrowp = 0.f;
#pragma unroll
      for (int fd = 0; fd < 4; ++fd) oacc[fd] = (f32x4)0.f;
    }

    const u16* ksb = &Ks[0][0] + cur * 4096;
    const u16* vsb = &Vs[0][0] + cur * 4096;

    // S^T = K Q^T  (lane: q = li fixed; kv = fj*16 + g*4 + r)
    f32x4 sfr[4] = {};
    __builtin_amdgcn_s_setprio(1);
#pragma unroll
    for (int kk = 0; kk < 2; ++kk) {
      s16x8 kf[4];
#pragma unroll
      for (int fj = 0; fj < 4; ++fj) kf[fj] = *(const s16x8*)&ksb[foff[kk][fj]];
#pragma unroll
      for (int fj = 0; fj < 4; ++fj) sfr[fj] = mfma_bf16(kf[fj], qf[kk], sfr[fj]);
    }
    __builtin_amdgcn_s_setprio(0);

    if (t == qt) {                           // diagonal tile: causal elem mask
#pragma unroll
      for (int fj = 0; fj < 4; ++fj)
#pragma unroll
        for (int r = 0; r < 4; ++r) {
          int jj = j0 + fj * 16 + g * 4 + r;
          if (jj > qglob) sfr[fj][r] = -1e30f;
        }
    }

    // lane-local max; cross-lane reduce ONLY when threshold exceeded (T13 ext)
    float mx = sfr[0][0];
#pragma unroll
    for (int fj = 0; fj < 4; ++fj)
#pragma unroll
      for (int r = 0; r < 4; ++r) mx = fmaxf(mx, sfr[fj][r]);

    bool need = (mx - mrow) * cexp > thr;
    if (__any(need)) {
      float m0 = mx;
      m0 = fmaxf(m0, __shfl_xor(m0, 16));
      m0 = fmaxf(m0, __shfl_xor(m0, 32));
      float mnew = fmaxf(mrow, m0);
      float sc = exp2f((mrow - mnew) * cexp);
      mrow = mnew;
      lrowp *= sc;
#pragma unroll
      for (int fd = 0; fd < 4; ++fd)
#pragma unroll
        for (int r = 0; r < 4; ++r) oacc[fd][r] *= sc;
    }

    // exp (bounded by 2^thr), per-lane partial sum, pack P to LDS
    float rs = 0.f;
#pragma unroll
    for (int fj = 0; fj < 4; ++fj) {
      float p0 = exp2f((sfr[fj][0] - mrow) * cexp);
      float p1 = exp2f((sfr[fj][1] - mrow) * cexp);
      float p2 = exp2f((sfr[fj][2] - mrow) * cexp);
      float p3 = exp2f((sfr[fj][3] - mrow) * cexp);
      rs += (p0 + p1) + (p2 + p3);
      u32x2 wv = { cvtpk(p0, p1), cvtpk(p2, p3) };
      *(u32x2*)&pl[pwoff[fj]] = wv;
    }
    lrowp += rs;                             // per-lane partial; no shfl here

    // O^T += V^T P^T
    __builtin_amdgcn_s_setprio(1);
#pragma unroll
    for (int kk = 0; kk < 2; ++kk) {
      s16x8 pf = *(const s16x8*)&pl[proff[kk]];
      s16x8 vf[4];
#pragma unroll
      for (int fd = 0; fd < 4; ++fd) vf[fd] = *(const s16x8*)&vsb[foff[kk][fd]];
#pragma unroll
      for (int fd = 0; fd < 4; ++fd) oacc[fd] = mfma_bf16(vf[fd], pf, oacc[fd]);
    }
    __builtin_amdgcn_s_setprio(0);

    if (t == qt) {                           // q-tile done: reduce l, write out
      float lr = lrowp;
      lr += __shfl_xor(lr, 16);
      lr += __shfl_xor(lr, 32);
      float inv = 1.f / lr;
      u16* ob = out + (size_t)(b * 2048 + qglob) * 1024 + h * 64;
#pragma unroll
      for (int fd = 0; fd < 4; ++fd) {
        u32x2 wv = { cvtpk(oacc[fd][0] * inv, oacc[fd][1] * inv),
                     cvtpk(oacc[fd][2] * inv, oacc[fd][3] * inv) };
        *(u32x2*)&ob[fd * 16 + g * 4] = wv;
      }
    }

    __syncthreads();                         // drains prefetch; buf swap safe
  }
}

// --- launch ------------------------------------------------------------------

extern "C" void kernel_launch(void* const* d_in, const int* in_sizes, int n_in,
                              void* d_out, int out_size, void* d_ws, size_t ws_size,
                              hipStream_t stream) {
  const float* x  = (const float*)d_in[0];
  const float* Wq = (const float*)d_in[1];
  const float* Wk = (const float*)d_in[2];
  const float* Wv = (const float*)d_in[3];
  const float* Wp = (const float*)d_in[4];
  const float* bp = (const float*)d_in[5];
  (void)in_sizes; (void)n_in; (void)out_size; (void)ws_size;

  char* ws = (char*)d_ws;
  u16* xb    = (u16*)(ws);                   // [8192][1024]  16 MB
  u16* wqkvb = (u16*)(ws + 16777216);        // [3072][1024]   6 MB
  u16* wpb   = (u16*)(ws + 23068672);        // [1024][1024]   2 MB
  u16* qkv   = (u16*)(ws + 25165824);        // [8192][3072]  48 MB (v third unused)
  u16* vT    = (u16*)(ws + 75497472);        // [64][64][2048] 16 MB
  u16* ao    = (u16*)(ws + 92274688);        // [8192][1024]  16 MB

  cvt_all_kernel<<<16896, 256, 0, stream>>>(x, Wq, Wk, Wv, Wp, xb, wqkvb, wpb);

  gemm_bt_kernel<2><<<dim3(64, 24), 256, 0, stream>>>(
      xb, wqkvb, (void*)qkv, nullptr, vT, 1024, 3072);

  attn_kernel<<<1024, 256, 0, stream>>>(qkv, vT, ao);

  gemm_bt_kernel<1><<<dim3(64, 8), 256, 0, stream>>>(
      ao, wpb, d_out, bp, nullptr, 1024, 1024);
}

// Round 10
// 174.637 us; speedup vs baseline: 1.0576x; 1.0576x over previous
//
#include <hip/hip_runtime.h>
#include <stdint.h>

// ---------------------------------------------------------------------------
// MultiHeadAttention B=4 T=2048 C=1024 H=16 D=64  (fp32 in/out, causal)
// Pipeline: cvt(bf16, fused) -> GEMM(QKV, v transposed) -> flash-attn -> GEMM(proj)+bias
// Round-10: revert GEMM swizzle (L2-thrash, +13us); attn v9 = v6 skeleton with
// KVBLK=128 (17 iters, half the barriers per unit work).
// ---------------------------------------------------------------------------

typedef unsigned short u16;
typedef __attribute__((ext_vector_type(8))) short    s16x8;
typedef __attribute__((ext_vector_type(4))) float    f32x4;
typedef __attribute__((ext_vector_type(2))) uint32_t u32x2;

// --- helpers ---------------------------------------------------------------

__device__ __forceinline__ u16 f2b(float f) {  // f32 -> bf16 RNE
  union { float f; uint32_t u; } v; v.f = f;
  uint32_t r = v.u + 0x7FFFu + ((v.u >> 16) & 1u);
  return (u16)(r >> 16);
}

__device__ __forceinline__ uint32_t cvtpk(float a, float b) {  // [lo=bf16(a), hi=bf16(b)]
  uint32_t r;
  asm("v_cvt_pk_bf16_f32 %0, %1, %2" : "=v"(r) : "v"(a), "v"(b));
  return r;
}

// v_mfma_f32_16x16x32_bf16. A: lane holds A[m=l&15][8k contig]; B: B^T[n=l&15][8k contig]
// C/D: row=(l>>4)*4+reg, col=l&15
__device__ __forceinline__ f32x4 mfma_bf16(s16x8 a, s16x8 b, f32x4 c) {
  asm("v_mfma_f32_16x16x32_bf16 %0, %1, %2, %0" : "+v"(c) : "v"(a), "v"(b));
  return c;
}

// async global->LDS, 16B per lane. LDS dest is wave-uniform base + lane*16.
__device__ __forceinline__ void gload_lds16(const void* g, void* l) {
  __builtin_amdgcn_global_load_lds(
      (__attribute__((address_space(1))) void*)(uintptr_t)g,
      (__attribute__((address_space(3))) void*)(uint32_t)(uintptr_t)l,
      16, 0, 0);
}

// --- fused conversion kernel -------------------------------------------------
// blocks [0,4096): x -> xb (8 elems/thread)
// blocks [4096,4608): Wp -> wpb (8 elems/thread)
// blocks [4608,16896): Wq/Wk/Wv gather -> wqkvb [3*H*D][C] (1 elem/thread)

__global__ void cvt_all_kernel(const float* __restrict__ x, const float* __restrict__ Wq,
                               const float* __restrict__ Wk, const float* __restrict__ Wv,
                               const float* __restrict__ Wp, u16* __restrict__ xb,
                               u16* __restrict__ wqkvb, u16* __restrict__ wpb) {
  int bid = blockIdx.x;
  if (bid < 4608) {
    const float* src = (bid < 4096) ? x : Wp;
    u16* dst = (bid < 4096) ? xb : wpb;
    size_t i = (size_t)((bid < 4096) ? bid : (bid - 4096)) * 256 + threadIdx.x;
    const f32x4* pp = (const f32x4*)(src + i * 8);
    f32x4 a = pp[0], b2 = pp[1];
    s16x8 o;
    o[0]=(short)f2b(a[0]); o[1]=(short)f2b(a[1]); o[2]=(short)f2b(a[2]); o[3]=(short)f2b(a[3]);
    o[4]=(short)f2b(b2[0]); o[5]=(short)f2b(b2[1]); o[6]=(short)f2b(b2[2]); o[7]=(short)f2b(b2[3]);
    *(s16x8*)(dst + i * 8) = o;
  } else {
    int idx = (bid - 4608) * 256 + threadIdx.x;
    int sel = idx >> 20;
    int rem = idx & 1048575;
    int n = rem >> 10, c = rem & 1023;
    int h = n >> 6, d = n & 63;
    const float* W = (sel == 0) ? Wq : ((sel == 1) ? Wk : Wv);
    wqkvb[idx] = f2b(W[h * 65536 + c * 64 + d]);
  }
}

// --- GEMM: C[M][N] = A[M][K] * B[N][K]^T  (bf16 in, 128x128 tile, BK=64) ----
// MODE 1: f32 out + bias.  MODE 2: qkv: cols<2048 -> bf16 C; v cols -> vT transposed.
// No block swizzle: default xy dispatch keeps resident working set L2-fit
// (round-9 lesson: bm-major chunking thrashed the 4MB L2, +13us).

template <int MODE>
__global__ __launch_bounds__(256) void gemm_bt_kernel(
    const u16* __restrict__ A, const u16* __restrict__ B, void* __restrict__ Cout,
    const float* __restrict__ bias, u16* __restrict__ vTout, int K, int ldc)
{
  __shared__ __attribute__((aligned(16))) u16 As[128 * 64];
  __shared__ __attribute__((aligned(16))) u16 Bs[128 * 64];

  const int tid  = threadIdx.x;
  const int lane = tid & 63;
  const int w    = tid >> 6;
  const int wm   = w >> 1, wn = w & 1;
  const int g    = lane >> 4;
  const int li   = lane & 15;
  const size_t bm = (size_t)blockIdx.x * 128;
  const size_t bn = (size_t)blockIdx.y * 128;

  f32x4 acc[4][4] = {};

  const int kIters = K >> 6;
  for (int kt = 0; kt < kIters; ++kt) {
    const int kb = kt * 64;
#pragma unroll
    for (int i = 0; i < 4; ++i) {
      int c = i * 256 + tid;
      int row = c >> 3, sl = c & 7;
      int ss = sl ^ (row & 7);
      gload_lds16(A + (bm + row) * K + kb + ss * 8, &As[c * 8]);
      gload_lds16(B + (bn + row) * K + kb + ss * 8, &Bs[c * 8]);
    }
    __syncthreads();
#pragma unroll
    for (int ks = 0; ks < 2; ++ks) {
      s16x8 af[4], bfr[4];
#pragma unroll
      for (int f = 0; f < 4; ++f) {
        int ra = wm * 64 + f * 16 + li;
        int sa = (ks * 4 + g) ^ (ra & 7);
        af[f] = *(const s16x8*)&As[ra * 64 + sa * 8];
        int rb = wn * 64 + f * 16 + li;
        int sb = (ks * 4 + g) ^ (rb & 7);
        bfr[f] = *(const s16x8*)&Bs[rb * 64 + sb * 8];
      }
#pragma unroll
      for (int mi = 0; mi < 4; ++mi)
#pragma unroll
        for (int ni = 0; ni < 4; ++ni)
          acc[mi][ni] = mfma_bf16(af[mi], bfr[ni], acc[mi][ni]);
    }
    __syncthreads();
  }

  if constexpr (MODE == 1) {
#pragma unroll
    for (int ni = 0; ni < 4; ++ni) {
      size_t col = bn + wn * 64 + ni * 16 + li;
      float bv = bias[col];
#pragma unroll
      for (int mi = 0; mi < 4; ++mi)
#pragma unroll
        for (int r = 0; r < 4; ++r) {
          size_t row = bm + wm * 64 + mi * 16 + g * 4 + r;
          ((float*)Cout)[row * ldc + col] = acc[mi][ni][r] + bv;
        }
    }
  } else {
    if (bn < 2048) {                 // q|k region: bf16 into qkv
#pragma unroll
      for (int ni = 0; ni < 4; ++ni) {
        size_t col = bn + wn * 64 + ni * 16 + li;
#pragma unroll
        for (int mi = 0; mi < 4; ++mi)
#pragma unroll
          for (int r = 0; r < 4; ++r) {
            size_t row = bm + wm * 64 + mi * 16 + g * 4 + r;
            ((u16*)Cout)[row * ldc + col] = f2b(acc[mi][ni][r]);
          }
      }
    } else {                         // v region: write transposed into vT[bh][d][t]
      const int hb = (int)((bn - 2048) >> 6) + wn;
      const int bb = (int)(bm >> 11);
      const int t0b = ((int)bm & 2047) + wm * 64 + g * 4;
      u16* vrow = vTout + (size_t)((bb * 16 + hb) * 64) * 2048;
#pragma unroll
      for (int ni = 0; ni < 4; ++ni) {
        u16* vd_ = vrow + (size_t)(ni * 16 + li) * 2048;
#pragma unroll
        for (int mi = 0; mi < 4; ++mi) {
          u32x2 wv = { cvtpk(acc[mi][ni][0], acc[mi][ni][1]),
                       cvtpk(acc[mi][ni][2], acc[mi][ni][3]) };
          *(u32x2*)&vd_[t0b + mi * 16] = wv;
        }
      }
    }
  }
}

// --- flash attention (causal) v9 ---------------------------------------------
// v6 sync skeleton (stage -> compute -> one __syncthreads), KVBLK=128:
// 17 iterations/block (vs 33) -> half the barriers+drains per unit work.
// QBLK=64 (4 waves x 16 q), causal pairing p=0..15: q-tiles (31-p) then (p);
// nA=((31-p)>>1)+1, nB=(p>>1)+1, nA+nB==17 for all p. Lane-local softmax
// (q=li), per-lane lrow partials, __any-gated max-reduce. LDS 80KB -> 2/CU.

__global__ __launch_bounds__(256, 2) void attn_kernel(const u16* __restrict__ qkv,
                                                      const u16* __restrict__ vT,
                                                      u16* __restrict__ out) {
  __shared__ __attribute__((aligned(16))) u16 Ks[2][128 * 64];   // [kv][d]
  __shared__ __attribute__((aligned(16))) u16 Vs[2][64 * 128];   // [d][t]
  __shared__ __attribute__((aligned(16))) u16 Ps[4][16 * 128];   // per-wave [q][kv]

  const int id  = blockIdx.x;                // 1024 blocks
  const int xcd = id & 7;
  const int rr  = id >> 3;
  const int bh  = xcd * 8 + (rr & 7);        // 8 bh per XCD
  const int p   = rr >> 3;                   // 0..15

  const int b = bh >> 4, h = bh & 15;
  const int tid = threadIdx.x;
  const int lane = tid & 63;
  const int w = tid >> 6;
  const int g = lane >> 4, li = lane & 15;

  const int nA = ((31 - p) >> 1) + 1;
  const int nB = (p >> 1) + 1;
  const int nTot = 17;                       // nA + nB == 17 for all p

  const u16* kbase = qkv + (size_t)(b * 2048) * 3072 + 1024 + h * 64;
  const u16* vtb   = vT + (size_t)bh * 64 * 2048;
  u16* pl = Ps[w];

  // --- staging offsets (16B slots, row-XOR swizzle; i-independent keys) ---
  // K tile [128][64]: c = i*256+tid -> row = i*32 + (tid>>3), slot = tid&7
  const int kge0 = (tid >> 3) * 3072 + (((tid & 7) ^ ((tid >> 3) & 7)) * 8);
  // V tile [64][128]: c -> row = i*16 + (tid>>4), slot = tid&15
  const int vge0 = (tid >> 4) * 2048 + (((tid & 15) ^ ((tid >> 4) & 7)) * 8);
  u16* const kd0 = &Ks[0][tid * 8];
  u16* const vd0 = &Vs[0][tid * 8];

  // --- fragment read offsets ---
  int foffK[2][8];                           // K frags: rk = fj*16+li, 8 slots/row
#pragma unroll
  for (int kk = 0; kk < 2; ++kk)
#pragma unroll
    for (int fj = 0; fj < 8; ++fj) {
      int rk = fj * 16 + li;
      foffK[kk][fj] = rk * 64 + (((kk * 4 + g) ^ (rk & 7)) * 8);
    }
  int foffV[4][4];                           // V frags: rv = fd*16+li, 16 slots/row
#pragma unroll
  for (int cc = 0; cc < 4; ++cc)
#pragma unroll
    for (int fd = 0; fd < 4; ++fd) {
      int rv = fd * 16 + li;
      foffV[cc][fd] = rv * 128 + (((cc * 4 + g) ^ (rv & 7)) * 8);
    }
  // P [16 q][128 kv]: 16 slots of 16B per row, XOR key li&15 (write==read key).
  int pwoff[8], proff[4];
#pragma unroll
  for (int fj = 0; fj < 8; ++fj)             // write: slot fj*2+(g>>1), half (g&1)
    pwoff[fj] = li * 128 + (((fj * 2 + (g >> 1)) ^ (li & 15)) * 8) + (g & 1) * 4;
#pragma unroll
  for (int cc = 0; cc < 4; ++cc)             // read: slot cc*4+g (one b128)
    proff[cc] = li * 128 + (((cc * 4 + g) ^ (li & 15)) * 8);

  auto stage = [&](int buf, int j0) {
    const u16* kp = kbase + (size_t)j0 * 3072 + kge0;
    const u16* vp = vtb + j0 + vge0;
    u16* kd = kd0 + buf * 8192;
    u16* vd = vd0 + buf * 8192;
#pragma unroll
    for (int i = 0; i < 4; ++i) {
      gload_lds16(kp + i * 98304, kd + i * 2048);   // i*32 rows * 3072
      gload_lds16(vp + i * 32768, vd + i * 2048);   // i*16 rows * 2048
    }
  };

  stage(0, 0);
  __syncthreads();

  s16x8 qf[2];
  f32x4 oacc[4];
  float mrow = -1e30f, lrowp = 0.f;
  int qglob = 0;
  const float cexp = 0.18033688011112042f;   // (1/sqrt(64)) * log2(e)
  const float thr = 8.0f;

  for (int s = 0; s < nTot; ++s) {
    const int cur = s & 1;
    const bool inA = s < nA;
    const int t  = inA ? s : s - nA;
    const int qt = inA ? (31 - p) : p;
    const int nq = inA ? nA : nB;
    const int j0 = t * 128;

    if (s + 1 < nTot) {                      // prefetch next tile before compute
      int t1 = (s + 1 < nA) ? (s + 1) : (s + 1 - nA);
      stage(cur ^ 1, t1 * 128);
    }

    if (t == 0) {                            // new q-tile: load Q frags, reset state
      qglob = qt * 64 + w * 16 + li;
      const u16* qbase = qkv + (size_t)(b * 2048 + qglob) * 3072 + h * 64;
#pragma unroll
      for (int kk = 0; kk < 2; ++kk)
        qf[kk] = *(const s16x8*)&qbase[kk * 32 + g * 8];
      mrow = -1e30f; lrowp = 0.f;
#pragma unroll
      for (int fd = 0; fd < 4; ++fd) oacc[fd] = (f32x4)0.f;
    }

    const u16* ksb = &Ks[0][0] + cur * 8192;
    const u16* vsb = &Vs[0][0] + cur * 8192;

    // S^T = K Q^T  (lane: q = li fixed; kv = fj*16 + g*4 + r, fj = 0..7)
    f32x4 sfr[8];
#pragma unroll
    for (int fj = 0; fj < 8; ++fj) sfr[fj] = (f32x4)0.f;
    __builtin_amdgcn_s_setprio(1);
#pragma unroll
    for (int kk = 0; kk < 2; ++kk) {
      s16x8 kf[8];
#pragma unroll
      for (int fj = 0; fj < 8; ++fj) kf[fj] = *(const s16x8*)&ksb[foffK[kk][fj]];
#pragma unroll
      for (int fj = 0; fj < 8; ++fj) sfr[fj] = mfma_bf16(kf[fj], qf[kk], sfr[fj]);
    }
    __builtin_amdgcn_s_setprio(0);

    if (t == nq - 1) {                       // diagonal tile: causal elem mask
#pragma unroll
      for (int fj = 0; fj < 8; ++fj)
#pragma unroll
        for (int r = 0; r < 4; ++r) {
          int jj = j0 + fj * 16 + g * 4 + r;
          if (jj > qglob) sfr[fj][r] = -1e30f;
        }
    }

    // lane-local max; cross-lane reduce ONLY when threshold exceeded (T13 ext)
    float mx = sfr[0][0];
#pragma unroll
    for (int fj = 0; fj < 8; ++fj)
#pragma unroll
      for (int r = 0; r < 4; ++r) mx = fmaxf(mx, sfr[fj][r]);

    bool need = (mx - mrow) * cexp > thr;
    if (__any(need)) {
      float m0 = mx;
      m0 = fmaxf(m0, __shfl_xor(m0, 16));
      m0 = fmaxf(m0, __shfl_xor(m0, 32));
      float mnew = fmaxf(mrow, m0);
      float sc = exp2f((mrow - mnew) * cexp);
      mrow = mnew;
      lrowp *= sc;
#pragma unroll
      for (int fd = 0; fd < 4; ++fd)
#pragma unroll
        for (int r = 0; r < 4; ++r) oacc[fd][r] *= sc;
    }

    // exp (bounded by 2^thr), per-lane partial sum, pack P to LDS
    float rs = 0.f;
#pragma unroll
    for (int fj = 0; fj < 8; ++fj) {
      float p0 = exp2f((sfr[fj][0] - mrow) * cexp);
      float p1 = exp2f((sfr[fj][1] - mrow) * cexp);
      float p2 = exp2f((sfr[fj][2] - mrow) * cexp);
      float p3 = exp2f((sfr[fj][3] - mrow) * cexp);
      rs += (p0 + p1) + (p2 + p3);
      u32x2 wv = { cvtpk(p0, p1), cvtpk(p2, p3) };
      *(u32x2*)&pl[pwoff[fj]] = wv;
    }
    lrowp += rs;                             // per-lane partial; no shfl here

    // O^T += V^T P^T  (4 K-chunks of 32 kv each)
    __builtin_amdgcn_s_setprio(1);
#pragma unroll
    for (int cc = 0; cc < 4; ++cc) {
      s16x8 pf = *(const s16x8*)&pl[proff[cc]];
      s16x8 vf[4];
#pragma unroll
      for (int fd = 0; fd < 4; ++fd) vf[fd] = *(const s16x8*)&vsb[foffV[cc][fd]];
#pragma unroll
      for (int fd = 0; fd < 4; ++fd) oacc[fd] = mfma_bf16(vf[fd], pf, oacc[fd]);
    }
    __builtin_amdgcn_s_setprio(0);

    if (t == nq - 1) {                       // q-tile done: reduce l, write out
      float lr = lrowp;
      lr += __shfl_xor(lr, 16);
      lr += __shfl_xor(lr, 32);
      float inv = 1.f / lr;
      u16* ob = out + (size_t)(b * 2048 + qglob) * 1024 + h * 64;
#pragma unroll
      for (int fd = 0; fd < 4; ++fd) {
        u32x2 wv = { cvtpk(oacc[fd][0] * inv, oacc[fd][1] * inv),
                     cvtpk(oacc[fd][2] * inv, oacc[fd][3] * inv) };
        *(u32x2*)&ob[fd * 16 + g * 4] = wv;
      }
    }

    __syncthreads();                         // drains prefetch; buf swap safe
  }
}

// --- launch ------------------------------------------------------------------

extern "C" void kernel_launch(void* const* d_in, const int* in_sizes, int n_in,
                              void* d_out, int out_size, void* d_ws, size_t ws_size,
                              hipStream_t stream) {
  const float* x  = (const float*)d_in[0];
  const float* Wq = (const float*)d_in[1];
  const float* Wk = (const float*)d_in[2];
  const float* Wv = (const float*)d_in[3];
  const float* Wp = (const float*)d_in[4];
  const float* bp = (const float*)d_in[5];
  (void)in_sizes; (void)n_in; (void)out_size; (void)ws_size;

  char* ws = (char*)d_ws;
  u16* xb    = (u16*)(ws);                   // [8192][1024]  16 MB
  u16* wqkvb = (u16*)(ws + 16777216);        // [3072][1024]   6 MB
  u16* wpb   = (u16*)(ws + 23068672);        // [1024][1024]   2 MB
  u16* qkv   = (u16*)(ws + 25165824);        // [8192][3072]  48 MB (v third unused)
  u16* vT    = (u16*)(ws + 75497472);        // [64][64][2048] 16 MB
  u16* ao    = (u16*)(ws + 92274688);        // [8192][1024]  16 MB

  cvt_all_kernel<<<16896, 256, 0, stream>>>(x, Wq, Wk, Wv, Wp, xb, wqkvb, wpb);

  gemm_bt_kernel<2><<<dim3(64, 24), 256, 0, stream>>>(
      xb, wqkvb, (void*)qkv, nullptr, vT, 1024, 3072);

  attn_kernel<<<1024, 256, 0, stream>>>(qkv, vT, ao);

  gemm_bt_kernel<1><<<dim3(64, 8), 256, 0, stream>>>(
      ao, wpb, d_out, bp, nullptr, 1024, 1024);
}

// Round 11
// 166.318 us; speedup vs baseline: 1.1105x; 1.0500x over previous
//
#include <hip/hip_runtime.h>
#include <stdint.h>

// ---------------------------------------------------------------------------
// MultiHeadAttention B=4 T=2048 C=1024 H=16 D=64  (fp32 in/out, causal)
// Pipeline: cvt(bf16, fused) -> GEMM(QKV, v transposed) -> flash-attn -> GEMM(proj)+bias
// Round-11: consolidation. v6 attn (85.8us, passed r6/r9) + fused cvt (passed
// r9/r10) + plain unswizzled 128^2 GEMMs (passed r10). All pairs verified.
// ---------------------------------------------------------------------------

typedef unsigned short u16;
typedef __attribute__((ext_vector_type(8))) short    s16x8;
typedef __attribute__((ext_vector_type(4))) float    f32x4;
typedef __attribute__((ext_vector_type(2))) uint32_t u32x2;

// --- helpers ---------------------------------------------------------------

__device__ __forceinline__ u16 f2b(float f) {  // f32 -> bf16 RNE
  union { float f; uint32_t u; } v; v.f = f;
  uint32_t r = v.u + 0x7FFFu + ((v.u >> 16) & 1u);
  return (u16)(r >> 16);
}

__device__ __forceinline__ uint32_t cvtpk(float a, float b) {  // [lo=bf16(a), hi=bf16(b)]
  uint32_t r;
  asm("v_cvt_pk_bf16_f32 %0, %1, %2" : "=v"(r) : "v"(a), "v"(b));
  return r;
}

// v_mfma_f32_16x16x32_bf16. A: lane holds A[m=l&15][8k contig]; B: B^T[n=l&15][8k contig]
// C/D: row=(l>>4)*4+reg, col=l&15
__device__ __forceinline__ f32x4 mfma_bf16(s16x8 a, s16x8 b, f32x4 c) {
  asm("v_mfma_f32_16x16x32_bf16 %0, %1, %2, %0" : "+v"(c) : "v"(a), "v"(b));
  return c;
}

// async global->LDS, 16B per lane. LDS dest is wave-uniform base + lane*16.
__device__ __forceinline__ void gload_lds16(const void* g, void* l) {
  __builtin_amdgcn_global_load_lds(
      (__attribute__((address_space(1))) void*)(uintptr_t)g,
      (__attribute__((address_space(3))) void*)(uint32_t)(uintptr_t)l,
      16, 0, 0);
}

// --- fused conversion kernel -------------------------------------------------
// blocks [0,4096): x -> xb (8 elems/thread)
// blocks [4096,4608): Wp -> wpb (8 elems/thread)
// blocks [4608,16896): Wq/Wk/Wv gather -> wqkvb [3*H*D][C] (1 elem/thread)

__global__ void cvt_all_kernel(const float* __restrict__ x, const float* __restrict__ Wq,
                               const float* __restrict__ Wk, const float* __restrict__ Wv,
                               const float* __restrict__ Wp, u16* __restrict__ xb,
                               u16* __restrict__ wqkvb, u16* __restrict__ wpb) {
  int bid = blockIdx.x;
  if (bid < 4608) {
    const float* src = (bid < 4096) ? x : Wp;
    u16* dst = (bid < 4096) ? xb : wpb;
    size_t i = (size_t)((bid < 4096) ? bid : (bid - 4096)) * 256 + threadIdx.x;
    const f32x4* pp = (const f32x4*)(src + i * 8);
    f32x4 a = pp[0], b2 = pp[1];
    s16x8 o;
    o[0]=(short)f2b(a[0]); o[1]=(short)f2b(a[1]); o[2]=(short)f2b(a[2]); o[3]=(short)f2b(a[3]);
    o[4]=(short)f2b(b2[0]); o[5]=(short)f2b(b2[1]); o[6]=(short)f2b(b2[2]); o[7]=(short)f2b(b2[3]);
    *(s16x8*)(dst + i * 8) = o;
  } else {
    int idx = (bid - 4608) * 256 + threadIdx.x;
    int sel = idx >> 20;
    int rem = idx & 1048575;
    int n = rem >> 10, c = rem & 1023;
    int h = n >> 6, d = n & 63;
    const float* W = (sel == 0) ? Wq : ((sel == 1) ? Wk : Wv);
    wqkvb[idx] = f2b(W[h * 65536 + c * 64 + d]);
  }
}

// --- GEMM: C[M][N] = A[M][K] * B[N][K]^T  (bf16 in, 128x128 tile, BK=64) ----
// MODE 1: f32 out + bias.  MODE 2: qkv: cols<2048 -> bf16 C; v cols -> vT transposed.
// No block swizzle: default xy dispatch keeps resident working set L2-fit
// (round-9 lesson: bm-major chunking thrashed the 4MB L2, +13us).

template <int MODE>
__global__ __launch_bounds__(256) void gemm_bt_kernel(
    const u16* __restrict__ A, const u16* __restrict__ B, void* __restrict__ Cout,
    const float* __restrict__ bias, u16* __restrict__ vTout, int K, int ldc)
{
  __shared__ __attribute__((aligned(16))) u16 As[128 * 64];
  __shared__ __attribute__((aligned(16))) u16 Bs[128 * 64];

  const int tid  = threadIdx.x;
  const int lane = tid & 63;
  const int w    = tid >> 6;
  const int wm   = w >> 1, wn = w & 1;
  const int g    = lane >> 4;
  const int li   = lane & 15;
  const size_t bm = (size_t)blockIdx.x * 128;
  const size_t bn = (size_t)blockIdx.y * 128;

  f32x4 acc[4][4] = {};

  const int kIters = K >> 6;
  for (int kt = 0; kt < kIters; ++kt) {
    const int kb = kt * 64;
#pragma unroll
    for (int i = 0; i < 4; ++i) {
      int c = i * 256 + tid;
      int row = c >> 3, sl = c & 7;
      int ss = sl ^ (row & 7);
      gload_lds16(A + (bm + row) * K + kb + ss * 8, &As[c * 8]);
      gload_lds16(B + (bn + row) * K + kb + ss * 8, &Bs[c * 8]);
    }
    __syncthreads();
#pragma unroll
    for (int ks = 0; ks < 2; ++ks) {
      s16x8 af[4], bfr[4];
#pragma unroll
      for (int f = 0; f < 4; ++f) {
        int ra = wm * 64 + f * 16 + li;
        int sa = (ks * 4 + g) ^ (ra & 7);
        af[f] = *(const s16x8*)&As[ra * 64 + sa * 8];
        int rb = wn * 64 + f * 16 + li;
        int sb = (ks * 4 + g) ^ (rb & 7);
        bfr[f] = *(const s16x8*)&Bs[rb * 64 + sb * 8];
      }
#pragma unroll
      for (int mi = 0; mi < 4; ++mi)
#pragma unroll
        for (int ni = 0; ni < 4; ++ni)
          acc[mi][ni] = mfma_bf16(af[mi], bfr[ni], acc[mi][ni]);
    }
    __syncthreads();
  }

  if constexpr (MODE == 1) {
#pragma unroll
    for (int ni = 0; ni < 4; ++ni) {
      size_t col = bn + wn * 64 + ni * 16 + li;
      float bv = bias[col];
#pragma unroll
      for (int mi = 0; mi < 4; ++mi)
#pragma unroll
        for (int r = 0; r < 4; ++r) {
          size_t row = bm + wm * 64 + mi * 16 + g * 4 + r;
          ((float*)Cout)[row * ldc + col] = acc[mi][ni][r] + bv;
        }
    }
  } else {
    if (bn < 2048) {                 // q|k region: bf16 into qkv
#pragma unroll
      for (int ni = 0; ni < 4; ++ni) {
        size_t col = bn + wn * 64 + ni * 16 + li;
#pragma unroll
        for (int mi = 0; mi < 4; ++mi)
#pragma unroll
          for (int r = 0; r < 4; ++r) {
            size_t row = bm + wm * 64 + mi * 16 + g * 4 + r;
            ((u16*)Cout)[row * ldc + col] = f2b(acc[mi][ni][r]);
          }
      }
    } else {                         // v region: write transposed into vT[bh][d][t]
      const int hb = (int)((bn - 2048) >> 6) + wn;
      const int bb = (int)(bm >> 11);
      const int t0b = ((int)bm & 2047) + wm * 64 + g * 4;
      u16* vrow = vTout + (size_t)((bb * 16 + hb) * 64) * 2048;
#pragma unroll
      for (int ni = 0; ni < 4; ++ni) {
        u16* vd_ = vrow + (size_t)(ni * 16 + li) * 2048;
#pragma unroll
        for (int mi = 0; mi < 4; ++mi) {
          u32x2 wv = { cvtpk(acc[mi][ni][0], acc[mi][ni][1]),
                       cvtpk(acc[mi][ni][2], acc[mi][ni][3]) };
          *(u32x2*)&vd_[t0b + mi * 16] = wv;
        }
      }
    }
  }
}

// --- flash attention (causal) v6 — verified structure (passed r6, r9) --------
// QBLK=64 (4 waves x 16 q), 1024 blocks, 40KB LDS -> 4 blocks/CU.
// Per-lane lrow partials; __any-gated max-reduce; causal pairing p=0..15.
// Double-buffered K/V, prefetch-before-compute, one __syncthreads per iter.

__global__ __launch_bounds__(256, 4) void attn_kernel(const u16* __restrict__ qkv,
                                                      const u16* __restrict__ vT,
                                                      u16* __restrict__ out) {
  __shared__ __attribute__((aligned(16))) u16 Ks[2][64 * 64];
  __shared__ __attribute__((aligned(16))) u16 Vs[2][64 * 64];
  __shared__ __attribute__((aligned(16))) u16 Ps[4][16 * 64];

  const int id  = blockIdx.x;                // 1024 blocks
  const int xcd = id & 7;
  const int rr  = id >> 3;
  const int bh  = xcd * 8 + (rr & 7);        // 8 bh per XCD
  const int p   = rr >> 3;                   // 0..15

  const int b = bh >> 4, h = bh & 15;
  const int tid = threadIdx.x;
  const int lane = tid & 63;
  const int w = tid >> 6;
  const int g = lane >> 4, li = lane & 15;

  const int tA = 31 - p;
  const int nA = tA + 1;
  const int nTot = 33;                       // nA + p + 1

  const u16* kbase = qkv + (size_t)(b * 2048) * 3072 + 1024 + h * 64;
  const u16* vtb   = vT + (size_t)bh * 64 * 2048;
  u16* pl = Ps[w];

  // hoisted per-lane offsets
  const int srow = tid >> 3;
  const int ssl0 = (tid & 7) ^ (srow & 7);
  const int kge0 = srow * 3072 + ssl0 * 8;
  const int vge0 = srow * 2048 + ssl0 * 8;
  u16* const kd0 = &Ks[0][tid * 8];
  u16* const vd0 = &Vs[0][tid * 8];

  int foff[2][4];                            // kf/vf fragment offsets
#pragma unroll
  for (int kk = 0; kk < 2; ++kk)
#pragma unroll
    for (int fj = 0; fj < 4; ++fj) {
      int rk = fj * 16 + li;
      foff[kk][fj] = rk * 64 + (((kk * 4 + g) ^ (rk & 7)) * 8);
    }
  const int lsw = li & 14;
  int pwoff[4], proff[2];
#pragma unroll
  for (int fj = 0; fj < 4; ++fj) pwoff[fj] = li * 64 + (((4 * fj + g) ^ lsw) * 4);
#pragma unroll
  for (int kk = 0; kk < 2; ++kk) proff[kk] = li * 64 + (((8 * kk + 2 * g) ^ lsw) * 4);

  auto stage = [&](int buf, int j0) {
    const u16* kp = kbase + (size_t)j0 * 3072;
    const u16* vp = vtb + j0;
    u16* kd = kd0 + buf * 4096;
    u16* vd = vd0 + buf * 4096;
    gload_lds16(kp + kge0, kd);
    gload_lds16(kp + kge0 + 32 * 3072, kd + 2048);
    gload_lds16(vp + vge0, vd);
    gload_lds16(vp + vge0 + 32 * 2048, vd + 2048);
  };

  stage(0, 0);
  __syncthreads();

  s16x8 qf[2];
  f32x4 oacc[4];
  float mrow = -1e30f, lrowp = 0.f;
  int qglob = 0;
  const float cexp = 0.18033688011112042f;   // (1/sqrt(64)) * log2(e)
  const float thr = 8.0f;

  for (int s = 0; s < nTot; ++s) {
    const int cur = s & 1;
    const bool inA = s < nA;
    const int t  = inA ? s : s - nA;
    const int qt = inA ? tA : p;
    const int j0 = t * 64;

    if (s + 1 < nTot) {                      // prefetch next tile before compute
      int t1 = (s + 1 < nA) ? (s + 1) : (s + 1 - nA);
      stage(cur ^ 1, t1 * 64);
    }

    if (t == 0) {                            // new q-tile: load Q frags, reset state
      qglob = qt * 64 + w * 16 + li;
      const u16* qbase = qkv + (size_t)(b * 2048 + qglob) * 3072 + h * 64;
#pragma unroll
      for (int kk = 0; kk < 2; ++kk)
        qf[kk] = *(const s16x8*)&qbase[kk * 32 + g * 8];
      mrow = -1e30f; lrowp = 0.f;
#pragma unroll
      for (int fd = 0; fd < 4; ++fd) oacc[fd] = (f32x4)0.f;
    }

    const u16* ksb = &Ks[0][0] + cur * 4096;
    const u16* vsb = &Vs[0][0] + cur * 4096;

    // S^T = K Q^T  (lane: q = li fixed; kv = fj*16 + g*4 + r)
    f32x4 sfr[4] = {};
    __builtin_amdgcn_s_setprio(1);
#pragma unroll
    for (int kk = 0; kk < 2; ++kk) {
      s16x8 kf[4];
#pragma unroll
      for (int fj = 0; fj < 4; ++fj) kf[fj] = *(const s16x8*)&ksb[foff[kk][fj]];
#pragma unroll
      for (int fj = 0; fj < 4; ++fj) sfr[fj] = mfma_bf16(kf[fj], qf[kk], sfr[fj]);
    }
    __builtin_amdgcn_s_setprio(0);

    if (t == qt) {                           // diagonal tile: causal elem mask
#pragma unroll
      for (int fj = 0; fj < 4; ++fj)
#pragma unroll
        for (int r = 0; r < 4; ++r) {
          int jj = j0 + fj * 16 + g * 4 + r;
          if (jj > qglob) sfr[fj][r] = -1e30f;
        }
    }

    // lane-local max; cross-lane reduce ONLY when threshold exceeded (T13 ext)
    float mx = sfr[0][0];
#pragma unroll
    for (int fj = 0; fj < 4; ++fj)
#pragma unroll
      for (int r = 0; r < 4; ++r) mx = fmaxf(mx, sfr[fj][r]);

    bool need = (mx - mrow) * cexp > thr;
    if (__any(need)) {
      float m0 = mx;
      m0 = fmaxf(m0, __shfl_xor(m0, 16));
      m0 = fmaxf(m0, __shfl_xor(m0, 32));
      float mnew = fmaxf(mrow, m0);
      float sc = exp2f((mrow - mnew) * cexp);
      mrow = mnew;
      lrowp *= sc;
#pragma unroll
      for (int fd = 0; fd < 4; ++fd)
#pragma unroll
        for (int r = 0; r < 4; ++r) oacc[fd][r] *= sc;
    }

    // exp (bounded by 2^thr), per-lane partial sum, pack P to LDS
    float rs = 0.f;
#pragma unroll
    for (int fj = 0; fj < 4; ++fj) {
      float p0 = exp2f((sfr[fj][0] - mrow) * cexp);
      float p1 = exp2f((sfr[fj][1] - mrow) * cexp);
      float p2 = exp2f((sfr[fj][2] - mrow) * cexp);
      float p3 = exp2f((sfr[fj][3] - mrow) * cexp);
      rs += (p0 + p1) + (p2 + p3);
      u32x2 wv = { cvtpk(p0, p1), cvtpk(p2, p3) };
      *(u32x2*)&pl[pwoff[fj]] = wv;
    }
    lrowp += rs;                             // per-lane partial; no shfl here

    // O^T += V^T P^T
    __builtin_amdgcn_s_setprio(1);
#pragma unroll
    for (int kk = 0; kk < 2; ++kk) {
      s16x8 pf = *(const s16x8*)&pl[proff[kk]];
      s16x8 vf[4];
#pragma unroll
      for (int fd = 0; fd < 4; ++fd) vf[fd] = *(const s16x8*)&vsb[foff[kk][fd]];
#pragma unroll
      for (int fd = 0; fd < 4; ++fd) oacc[fd] = mfma_bf16(vf[fd], pf, oacc[fd]);
    }
    __builtin_amdgcn_s_setprio(0);

    if (t == qt) {                           // q-tile done: reduce l, write out
      float lr = lrowp;
      lr += __shfl_xor(lr, 16);
      lr += __shfl_xor(lr, 32);
      float inv = 1.f / lr;
      u16* ob = out + (size_t)(b * 2048 + qglob) * 1024 + h * 64;
#pragma unroll
      for (int fd = 0; fd < 4; ++fd) {
        u32x2 wv = { cvtpk(oacc[fd][0] * inv, oacc[fd][1] * inv),
                     cvtpk(oacc[fd][2] * inv, oacc[fd][3] * inv) };
        *(u32x2*)&ob[fd * 16 + g * 4] = wv;
      }
    }

    __syncthreads();                         // drains prefetch; buf swap safe
  }
}

// --- launch ------------------------------------------------------------------

extern "C" void kernel_launch(void* const* d_in, const int* in_sizes, int n_in,
                              void* d_out, int out_size, void* d_ws, size_t ws_size,
                              hipStream_t stream) {
  const float* x  = (const float*)d_in[0];
  const float* Wq = (const float*)d_in[1];
  const float* Wk = (const float*)d_in[2];
  const float* Wv = (const float*)d_in[3];
  const float* Wp = (const float*)d_in[4];
  const float* bp = (const float*)d_in[5];
  (void)in_sizes; (void)n_in; (void)out_size; (void)ws_size;

  char* ws = (char*)d_ws;
  u16* xb    = (u16*)(ws);                   // [8192][1024]  16 MB
  u16* wqkvb = (u16*)(ws + 16777216);        // [3072][1024]   6 MB
  u16* wpb   = (u16*)(ws + 23068672);        // [1024][1024]   2 MB
  u16* qkv   = (u16*)(ws + 25165824);        // [8192][3072]  48 MB (v third unused)
  u16* vT    = (u16*)(ws + 75497472);        // [64][64][2048] 16 MB
  u16* ao    = (u16*)(ws + 92274688);        // [8192][1024]  16 MB

  cvt_all_kernel<<<16896, 256, 0, stream>>>(x, Wq, Wk, Wv, Wp, xb, wqkvb, wpb);

  gemm_bt_kernel<2><<<dim3(64, 24), 256, 0, stream>>>(
      xb, wqkvb, (void*)qkv, nullptr, vT, 1024, 3072);

  attn_kernel<<<1024, 256, 0, stream>>>(qkv, vT, ao);

  gemm_bt_kernel<1><<<dim3(64, 8), 256, 0, stream>>>(
      ao, wpb, d_out, bp, nullptr, 1024, 1024);
}

// Round 12
// 154.791 us; speedup vs baseline: 1.1932x; 1.0745x over previous
//
#include <hip/hip_runtime.h>
#include <stdint.h>

// ---------------------------------------------------------------------------
// MultiHeadAttention B=4 T=2048 C=1024 H=16 D=64  (fp32 in/out, causal)
// Pipeline: cvt(bf16, fused) -> GEMM(QKV, v transposed) -> flash-attn -> GEMM(proj)+bias
// Round-12: single-change A/B vs round-11 (166.3us): attn exp2f -> raw
// v_exp_f32. Everything else byte-identical to the verified r11 build.
// ---------------------------------------------------------------------------

typedef unsigned short u16;
typedef __attribute__((ext_vector_type(8))) short    s16x8;
typedef __attribute__((ext_vector_type(4))) float    f32x4;
typedef __attribute__((ext_vector_type(2))) uint32_t u32x2;

// --- helpers ---------------------------------------------------------------

__device__ __forceinline__ u16 f2b(float f) {  // f32 -> bf16 RNE
  union { float f; uint32_t u; } v; v.f = f;
  uint32_t r = v.u + 0x7FFFu + ((v.u >> 16) & 1u);
  return (u16)(r >> 16);
}

__device__ __forceinline__ uint32_t cvtpk(float a, float b) {  // [lo=bf16(a), hi=bf16(b)]
  uint32_t r;
  asm("v_cvt_pk_bf16_f32 %0, %1, %2" : "=v"(r) : "v"(a), "v"(b));
  return r;
}

__device__ __forceinline__ float vexp2(float x) {  // 2^x, single v_exp_f32
  float r;
  asm("v_exp_f32 %0, %1" : "=v"(r) : "v"(x));
  return r;
}

// v_mfma_f32_16x16x32_bf16. A: lane holds A[m=l&15][8k contig]; B: B^T[n=l&15][8k contig]
// C/D: row=(l>>4)*4+reg, col=l&15
__device__ __forceinline__ f32x4 mfma_bf16(s16x8 a, s16x8 b, f32x4 c) {
  asm("v_mfma_f32_16x16x32_bf16 %0, %1, %2, %0" : "+v"(c) : "v"(a), "v"(b));
  return c;
}

// async global->LDS, 16B per lane. LDS dest is wave-uniform base + lane*16.
__device__ __forceinline__ void gload_lds16(const void* g, void* l) {
  __builtin_amdgcn_global_load_lds(
      (__attribute__((address_space(1))) void*)(uintptr_t)g,
      (__attribute__((address_space(3))) void*)(uint32_t)(uintptr_t)l,
      16, 0, 0);
}

// --- fused conversion kernel -------------------------------------------------
// blocks [0,4096): x -> xb (8 elems/thread)
// blocks [4096,4608): Wp -> wpb (8 elems/thread)
// blocks [4608,16896): Wq/Wk/Wv gather -> wqkvb [3*H*D][C] (1 elem/thread)

__global__ void cvt_all_kernel(const float* __restrict__ x, const float* __restrict__ Wq,
                               const float* __restrict__ Wk, const float* __restrict__ Wv,
                               const float* __restrict__ Wp, u16* __restrict__ xb,
                               u16* __restrict__ wqkvb, u16* __restrict__ wpb) {
  int bid = blockIdx.x;
  if (bid < 4608) {
    const float* src = (bid < 4096) ? x : Wp;
    u16* dst = (bid < 4096) ? xb : wpb;
    size_t i = (size_t)((bid < 4096) ? bid : (bid - 4096)) * 256 + threadIdx.x;
    const f32x4* pp = (const f32x4*)(src + i * 8);
    f32x4 a = pp[0], b2 = pp[1];
    s16x8 o;
    o[0]=(short)f2b(a[0]); o[1]=(short)f2b(a[1]); o[2]=(short)f2b(a[2]); o[3]=(short)f2b(a[3]);
    o[4]=(short)f2b(b2[0]); o[5]=(short)f2b(b2[1]); o[6]=(short)f2b(b2[2]); o[7]=(short)f2b(b2[3]);
    *(s16x8*)(dst + i * 8) = o;
  } else {
    int idx = (bid - 4608) * 256 + threadIdx.x;
    int sel = idx >> 20;
    int rem = idx & 1048575;
    int n = rem >> 10, c = rem & 1023;
    int h = n >> 6, d = n & 63;
    const float* W = (sel == 0) ? Wq : ((sel == 1) ? Wk : Wv);
    wqkvb[idx] = f2b(W[h * 65536 + c * 64 + d]);
  }
}

// --- GEMM: C[M][N] = A[M][K] * B[N][K]^T  (bf16 in, 128x128 tile, BK=64) ----
// MODE 1: f32 out + bias.  MODE 2: qkv: cols<2048 -> bf16 C; v cols -> vT transposed.
// No block swizzle: default xy dispatch keeps resident working set L2-fit
// (round-9 lesson: bm-major chunking thrashed the 4MB L2, +13us).

template <int MODE>
__global__ __launch_bounds__(256) void gemm_bt_kernel(
    const u16* __restrict__ A, const u16* __restrict__ B, void* __restrict__ Cout,
    const float* __restrict__ bias, u16* __restrict__ vTout, int K, int ldc)
{
  __shared__ __attribute__((aligned(16))) u16 As[128 * 64];
  __shared__ __attribute__((aligned(16))) u16 Bs[128 * 64];

  const int tid  = threadIdx.x;
  const int lane = tid & 63;
  const int w    = tid >> 6;
  const int wm   = w >> 1, wn = w & 1;
  const int g    = lane >> 4;
  const int li   = lane & 15;
  const size_t bm = (size_t)blockIdx.x * 128;
  const size_t bn = (size_t)blockIdx.y * 128;

  f32x4 acc[4][4] = {};

  const int kIters = K >> 6;
  for (int kt = 0; kt < kIters; ++kt) {
    const int kb = kt * 64;
#pragma unroll
    for (int i = 0; i < 4; ++i) {
      int c = i * 256 + tid;
      int row = c >> 3, sl = c & 7;
      int ss = sl ^ (row & 7);
      gload_lds16(A + (bm + row) * K + kb + ss * 8, &As[c * 8]);
      gload_lds16(B + (bn + row) * K + kb + ss * 8, &Bs[c * 8]);
    }
    __syncthreads();
#pragma unroll
    for (int ks = 0; ks < 2; ++ks) {
      s16x8 af[4], bfr[4];
#pragma unroll
      for (int f = 0; f < 4; ++f) {
        int ra = wm * 64 + f * 16 + li;
        int sa = (ks * 4 + g) ^ (ra & 7);
        af[f] = *(const s16x8*)&As[ra * 64 + sa * 8];
        int rb = wn * 64 + f * 16 + li;
        int sb = (ks * 4 + g) ^ (rb & 7);
        bfr[f] = *(const s16x8*)&Bs[rb * 64 + sb * 8];
      }
#pragma unroll
      for (int mi = 0; mi < 4; ++mi)
#pragma unroll
        for (int ni = 0; ni < 4; ++ni)
          acc[mi][ni] = mfma_bf16(af[mi], bfr[ni], acc[mi][ni]);
    }
    __syncthreads();
  }

  if constexpr (MODE == 1) {
#pragma unroll
    for (int ni = 0; ni < 4; ++ni) {
      size_t col = bn + wn * 64 + ni * 16 + li;
      float bv = bias[col];
#pragma unroll
      for (int mi = 0; mi < 4; ++mi)
#pragma unroll
        for (int r = 0; r < 4; ++r) {
          size_t row = bm + wm * 64 + mi * 16 + g * 4 + r;
          ((float*)Cout)[row * ldc + col] = acc[mi][ni][r] + bv;
        }
    }
  } else {
    if (bn < 2048) {                 // q|k region: bf16 into qkv
#pragma unroll
      for (int ni = 0; ni < 4; ++ni) {
        size_t col = bn + wn * 64 + ni * 16 + li;
#pragma unroll
        for (int mi = 0; mi < 4; ++mi)
#pragma unroll
          for (int r = 0; r < 4; ++r) {
            size_t row = bm + wm * 64 + mi * 16 + g * 4 + r;
            ((u16*)Cout)[row * ldc + col] = f2b(acc[mi][ni][r]);
          }
      }
    } else {                         // v region: write transposed into vT[bh][d][t]
      const int hb = (int)((bn - 2048) >> 6) + wn;
      const int bb = (int)(bm >> 11);
      const int t0b = ((int)bm & 2047) + wm * 64 + g * 4;
      u16* vrow = vTout + (size_t)((bb * 16 + hb) * 64) * 2048;
#pragma unroll
      for (int ni = 0; ni < 4; ++ni) {
        u16* vd_ = vrow + (size_t)(ni * 16 + li) * 2048;
#pragma unroll
        for (int mi = 0; mi < 4; ++mi) {
          u32x2 wv = { cvtpk(acc[mi][ni][0], acc[mi][ni][1]),
                       cvtpk(acc[mi][ni][2], acc[mi][ni][3]) };
          *(u32x2*)&vd_[t0b + mi * 16] = wv;
        }
      }
    }
  }
}

// --- flash attention (causal) v6 + vexp2 (single change vs round-11) ---------
// QBLK=64 (4 waves x 16 q), 1024 blocks, 40KB LDS -> 4 blocks/CU.
// Per-lane lrow partials; __any-gated max-reduce; causal pairing p=0..15.
// Double-buffered K/V, prefetch-before-compute, one __syncthreads per iter.
// exp2f -> raw v_exp_f32: safe here (args <= thr=8 post-gate; masked entries
// -> -1.8e29 -> 0; the first-tile gate always fires before any exp).

__global__ __launch_bounds__(256, 4) void attn_kernel(const u16* __restrict__ qkv,
                                                      const u16* __restrict__ vT,
                                                      u16* __restrict__ out) {
  __shared__ __attribute__((aligned(16))) u16 Ks[2][64 * 64];
  __shared__ __attribute__((aligned(16))) u16 Vs[2][64 * 64];
  __shared__ __attribute__((aligned(16))) u16 Ps[4][16 * 64];

  const int id  = blockIdx.x;                // 1024 blocks
  const int xcd = id & 7;
  const int rr  = id >> 3;
  const int bh  = xcd * 8 + (rr & 7);        // 8 bh per XCD
  const int p   = rr >> 3;                   // 0..15

  const int b = bh >> 4, h = bh & 15;
  const int tid = threadIdx.x;
  const int lane = tid & 63;
  const int w = tid >> 6;
  const int g = lane >> 4, li = lane & 15;

  const int tA = 31 - p;
  const int nA = tA + 1;
  const int nTot = 33;                       // nA + p + 1

  const u16* kbase = qkv + (size_t)(b * 2048) * 3072 + 1024 + h * 64;
  const u16* vtb   = vT + (size_t)bh * 64 * 2048;
  u16* pl = Ps[w];

  // hoisted per-lane offsets
  const int srow = tid >> 3;
  const int ssl0 = (tid & 7) ^ (srow & 7);
  const int kge0 = srow * 3072 + ssl0 * 8;
  const int vge0 = srow * 2048 + ssl0 * 8;
  u16* const kd0 = &Ks[0][tid * 8];
  u16* const vd0 = &Vs[0][tid * 8];

  int foff[2][4];                            // kf/vf fragment offsets
#pragma unroll
  for (int kk = 0; kk < 2; ++kk)
#pragma unroll
    for (int fj = 0; fj < 4; ++fj) {
      int rk = fj * 16 + li;
      foff[kk][fj] = rk * 64 + (((kk * 4 + g) ^ (rk & 7)) * 8);
    }
  const int lsw = li & 14;
  int pwoff[4], proff[2];
#pragma unroll
  for (int fj = 0; fj < 4; ++fj) pwoff[fj] = li * 64 + (((4 * fj + g) ^ lsw) * 4);
#pragma unroll
  for (int kk = 0; kk < 2; ++kk) proff[kk] = li * 64 + (((8 * kk + 2 * g) ^ lsw) * 4);

  auto stage = [&](int buf, int j0) {
    const u16* kp = kbase + (size_t)j0 * 3072;
    const u16* vp = vtb + j0;
    u16* kd = kd0 + buf * 4096;
    u16* vd = vd0 + buf * 4096;
    gload_lds16(kp + kge0, kd);
    gload_lds16(kp + kge0 + 32 * 3072, kd + 2048);
    gload_lds16(vp + vge0, vd);
    gload_lds16(vp + vge0 + 32 * 2048, vd + 2048);
  };

  stage(0, 0);
  __syncthreads();

  s16x8 qf[2];
  f32x4 oacc[4];
  float mrow = -1e30f, lrowp = 0.f;
  int qglob = 0;
  const float cexp = 0.18033688011112042f;   // (1/sqrt(64)) * log2(e)
  const float thr = 8.0f;

  for (int s = 0; s < nTot; ++s) {
    const int cur = s & 1;
    const bool inA = s < nA;
    const int t  = inA ? s : s - nA;
    const int qt = inA ? tA : p;
    const int j0 = t * 64;

    if (s + 1 < nTot) {                      // prefetch next tile before compute
      int t1 = (s + 1 < nA) ? (s + 1) : (s + 1 - nA);
      stage(cur ^ 1, t1 * 64);
    }

    if (t == 0) {                            // new q-tile: load Q frags, reset state
      qglob = qt * 64 + w * 16 + li;
      const u16* qbase = qkv + (size_t)(b * 2048 + qglob) * 3072 + h * 64;
#pragma unroll
      for (int kk = 0; kk < 2; ++kk)
        qf[kk] = *(const s16x8*)&qbase[kk * 32 + g * 8];
      mrow = -1e30f; lrowp = 0.f;
#pragma unroll
      for (int fd = 0; fd < 4; ++fd) oacc[fd] = (f32x4)0.f;
    }

    const u16* ksb = &Ks[0][0] + cur * 4096;
    const u16* vsb = &Vs[0][0] + cur * 4096;

    // S^T = K Q^T  (lane: q = li fixed; kv = fj*16 + g*4 + r)
    f32x4 sfr[4] = {};
    __builtin_amdgcn_s_setprio(1);
#pragma unroll
    for (int kk = 0; kk < 2; ++kk) {
      s16x8 kf[4];
#pragma unroll
      for (int fj = 0; fj < 4; ++fj) kf[fj] = *(const s16x8*)&ksb[foff[kk][fj]];
#pragma unroll
      for (int fj = 0; fj < 4; ++fj) sfr[fj] = mfma_bf16(kf[fj], qf[kk], sfr[fj]);
    }
    __builtin_amdgcn_s_setprio(0);

    if (t == qt) {                           // diagonal tile: causal elem mask
#pragma unroll
      for (int fj = 0; fj < 4; ++fj)
#pragma unroll
        for (int r = 0; r < 4; ++r) {
          int jj = j0 + fj * 16 + g * 4 + r;
          if (jj > qglob) sfr[fj][r] = -1e30f;
        }
    }

    // lane-local max; cross-lane reduce ONLY when threshold exceeded (T13 ext)
    float mx = sfr[0][0];
#pragma unroll
    for (int fj = 0; fj < 4; ++fj)
#pragma unroll
      for (int r = 0; r < 4; ++r) mx = fmaxf(mx, sfr[fj][r]);

    bool need = (mx - mrow) * cexp > thr;
    if (__any(need)) {
      float m0 = mx;
      m0 = fmaxf(m0, __shfl_xor(m0, 16));
      m0 = fmaxf(m0, __shfl_xor(m0, 32));
      float mnew = fmaxf(mrow, m0);
      float sc = vexp2((mrow - mnew) * cexp);
      mrow = mnew;
      lrowp *= sc;
#pragma unroll
      for (int fd = 0; fd < 4; ++fd)
#pragma unroll
        for (int r = 0; r < 4; ++r) oacc[fd][r] *= sc;
    }

    // exp (bounded by 2^thr), per-lane partial sum, pack P to LDS
    float rs = 0.f;
#pragma unroll
    for (int fj = 0; fj < 4; ++fj) {
      float p0 = vexp2((sfr[fj][0] - mrow) * cexp);
      float p1 = vexp2((sfr[fj][1] - mrow) * cexp);
      float p2 = vexp2((sfr[fj][2] - mrow) * cexp);
      float p3 = vexp2((sfr[fj][3] - mrow) * cexp);
      rs += (p0 + p1) + (p2 + p3);
      u32x2 wv = { cvtpk(p0, p1), cvtpk(p2, p3) };
      *(u32x2*)&pl[pwoff[fj]] = wv;
    }
    lrowp += rs;                             // per-lane partial; no shfl here

    // O^T += V^T P^T
    __builtin_amdgcn_s_setprio(1);
#pragma unroll
    for (int kk = 0; kk < 2; ++kk) {
      s16x8 pf = *(const s16x8*)&pl[proff[kk]];
      s16x8 vf[4];
#pragma unroll
      for (int fd = 0; fd < 4; ++fd) vf[fd] = *(const s16x8*)&vsb[foff[kk][fd]];
#pragma unroll
      for (int fd = 0; fd < 4; ++fd) oacc[fd] = mfma_bf16(vf[fd], pf, oacc[fd]);
    }
    __builtin_amdgcn_s_setprio(0);

    if (t == qt) {                           // q-tile done: reduce l, write out
      float lr = lrowp;
      lr += __shfl_xor(lr, 16);
      lr += __shfl_xor(lr, 32);
      float inv = 1.f / lr;
      u16* ob = out + (size_t)(b * 2048 + qglob) * 1024 + h * 64;
#pragma unroll
      for (int fd = 0; fd < 4; ++fd) {
        u32x2 wv = { cvtpk(oacc[fd][0] * inv, oacc[fd][1] * inv),
                     cvtpk(oacc[fd][2] * inv, oacc[fd][3] * inv) };
        *(u32x2*)&ob[fd * 16 + g * 4] = wv;
      }
    }

    __syncthreads();                         // drains prefetch; buf swap safe
  }
}

// --- launch ------------------------------------------------------------------

extern "C" void kernel_launch(void* const* d_in, const int* in_sizes, int n_in,
                              void* d_out, int out_size, void* d_ws, size_t ws_size,
                              hipStream_t stream) {
  const float* x  = (const float*)d_in[0];
  const float* Wq = (const float*)d_in[1];
  const float* Wk = (const float*)d_in[2];
  const float* Wv = (const float*)d_in[3];
  const float* Wp = (const float*)d_in[4];
  const float* bp = (const float*)d_in[5];
  (void)in_sizes; (void)n_in; (void)out_size; (void)ws_size;

  char* ws = (char*)d_ws;
  u16* xb    = (u16*)(ws);                   // [8192][1024]  16 MB
  u16* wqkvb = (u16*)(ws + 16777216);        // [3072][1024]   6 MB
  u16* wpb   = (u16*)(ws + 23068672);        // [1024][1024]   2 MB
  u16* qkv   = (u16*)(ws + 25165824);        // [8192][3072]  48 MB (v third unused)
  u16* vT    = (u16*)(ws + 75497472);        // [64][64][2048] 16 MB
  u16* ao    = (u16*)(ws + 92274688);        // [8192][1024]  16 MB

  cvt_all_kernel<<<16896, 256, 0, stream>>>(x, Wq, Wk, Wv, Wp, xb, wqkvb, wpb);

  gemm_bt_kernel<2><<<dim3(64, 24), 256, 0, stream>>>(
      xb, wqkvb, (void*)qkv, nullptr, vT, 1024, 3072);

  attn_kernel<<<1024, 256, 0, stream>>>(qkv, vT, ao);

  gemm_bt_kernel<1><<<dim3(64, 8), 256, 0, stream>>>(
      ao, wpb, d_out, bp, nullptr, 1024, 1024);
}